// Round 8
// baseline (1433.167 us; speedup 1.0000x reference)
//
#include <hip/hip_runtime.h>
#include <hip/hip_cooperative_groups.h>
#include <math.h>

namespace cg = cooperative_groups;

#define NT 30
#define TT 60
#define S  90
#define NN 48
#define SS (S*S)            // 8100
#define RSZ (NT*SS)         // 243000
#define NEGF (-1.0e9f)
#define PB 72               // bf16 LDS pitch (144B, 16B-aligned)
#define ACH 6               // nonterminals per work item
#define NCHUNK 5            // chunks per cell (5*6 = 30)
#define NBLKC 240           // >= max items per level (235)

typedef __attribute__((ext_vector_type(8))) short bf16x8;
typedef __attribute__((ext_vector_type(4))) float f32x4;

__device__ __forceinline__ unsigned ordKey(float f) {
    unsigned u = __float_as_uint(f);
    return (u & 0x80000000u) ? ~u : (u | 0x80000000u);
}
__device__ __forceinline__ float decKey(unsigned k) {
    unsigned u = (k & 0x80000000u) ? (k ^ 0x80000000u) : ~k;
    return __uint_as_float(u);
}
__device__ __forceinline__ unsigned short f2bf(float f) {
    unsigned u = __float_as_uint(f);
    return (unsigned short)((u + 0x7fffu + ((u >> 16) & 1u)) >> 16);
}

__global__ void k_rmax1(const float* __restrict__ rule, float* __restrict__ rpart) {
    __shared__ float red[256];
    float v = -INFINITY;
    for (int i = blockIdx.x * 256 + threadIdx.x; i < RSZ; i += 256 * 128)
        v = fmaxf(v, rule[i]);
    red[threadIdx.x] = v;
    __syncthreads();
    for (int s = 128; s > 0; s >>= 1) {
        if (threadIdx.x < s) red[threadIdx.x] = fmaxf(red[threadIdx.x], red[threadIdx.x + s]);
        __syncthreads();
    }
    if (threadIdx.x == 0) rpart[blockIdx.x] = red[0];
}

__global__ void k_rmax2(const float* __restrict__ rpart, float* __restrict__ rmax) {
    const int t = threadIdx.x;  // 64
    float v = fmaxf(rpart[t], rpart[t + 64]);
    for (int o = 32; o > 0; o >>= 1) v = fmaxf(v, __shfl_down(v, o));
    if (t == 0) rmax[0] = v;
}

// erule, bf16, tile-major matching the MFMA C-fragment:
// eruleB[((a*36 + bt*6 + ct)*64 + lane)*4 + reg] = bf16(exp(rule[a][bt*16+(lane>>4)*4+reg][ct*16+(lane&15)] - Rm))
__global__ void k_eruleB(const float* __restrict__ rule, const float* __restrict__ rmax,
                         unsigned short* __restrict__ eruleB) {
    const int a    = blockIdx.x;    // 30
    const int tIdx = blockIdx.y;    // 36
    const int lane = threadIdx.x;   // 64
    const int bt = tIdx / 6, ct = tIdx - bt * 6;
    const float Rm = rmax[0];
    ushort4 vv;
    unsigned short* pv = (unsigned short*)&vv;
#pragma unroll
    for (int reg = 0; reg < 4; ++reg) {
        int b = bt * 16 + (lane >> 4) * 4 + reg;
        int c = ct * 16 + (lane & 15);
        float val = (b < S && c < S) ? __expf(rule[a * SS + b * S + c] - Rm) : 0.f;
        pv[reg] = f2bf(val);
    }
    *(ushort4*)(eruleB + ((a * 36 + tIdx) * 64 + lane) * 4) = vv;
}

// 48 blocks x 96 threads: diag cells + mkey init.
__global__ void k_init(const float* __restrict__ unary, float* __restrict__ chart,
                       unsigned* __restrict__ mkey) {
    const int i = blockIdx.x;
    const int t = threadIdx.x;
    __shared__ float mxs;
    if (t < 64) {
        float v = (t < TT) ? unary[i * TT + t] : -INFINITY;
        for (int o = 32; o > 0; o >>= 1) v = fmaxf(v, __shfl_down(v, o));
        if (t == 0) mxs = v;
    }
    if (t < S) chart[(i * NN + i) * S + t] = (t < NT) ? NEGF : unary[i * TT + (t - NT)];
    __syncthreads();
    if (t < NN) mkey[i * NN + t] = (t == i) ? ordKey(mxs) : 0u;
}

// Cooperative kernel: all 47 levels with grid.sync between, plus final reduce.
__global__ __launch_bounds__(384, 1) void k_coop(const unsigned short* __restrict__ eruleB,
                                                 const float* __restrict__ rmax,
                                                 const float* __restrict__ root,
                                                 float* __restrict__ chart,
                                                 unsigned* __restrict__ mkey,
                                                 float* __restrict__ out) {
    cg::grid_group grid = cg::this_grid();
    const int tid  = threadIdx.x;
    const int lane = tid & 63;
    const int w    = tid >> 6;          // wave id = A-tile row

    __shared__ unsigned short elT[96 * PB];   // [b][m] bf16
    __shared__ unsigned short erT[96 * PB];   // [c][m] bf16
    __shared__ float ml[47], mr[47], wexp[47];
    __shared__ float part[ACH][6];
    __shared__ float Msh;

    const float Rm = rmax[0];

    for (int l = 1; l < NN; ++l) {
        const int items = (NN - l) * NCHUNK;
        if ((int)blockIdx.x < items) {
            const int s0    = blockIdx.x / NCHUNK;
            const int chunk = blockIdx.x - s0 * NCHUNK;
            const int j     = s0 + l;
            const int a0    = chunk * ACH;
            const int cell  = s0 * NN + j;

            // ---- scales from per-cell max table (wave 0) ----
            if (w == 0) {
                float msum = -INFINITY;
                if (lane < l) {
                    float a_ = decKey(mkey[s0 * NN + s0 + lane]);
                    float b_ = decKey(mkey[(s0 + lane + 1) * NN + j]);
                    ml[lane] = a_; mr[lane] = b_;
                    msum = a_ + b_;
                }
                float v = msum;
                for (int o = 32; o > 0; o >>= 1) v = fmaxf(v, __shfl_down(v, o));
                float M = __shfl(v, 0);
                if (lane == 0) Msh = M;
                if (lane < l) wexp[lane] = __expf(msum - M);
            }

            // ---- zero only the K-pad regions ----
            const int K  = (l > 32) ? 64 : 32;
            const int zc = K - l;
            for (int i = tid; i < 96 * zc; i += 384) {
                int x = i / zc, m = l + (i - x * zc);
                elT[x * PB + m] = 0; erT[x * PB + m] = 0;
            }
            for (int i = tid; i < 6 * l; i += 384) {
                int q = i / l;
                int x = 90 + q, m = i - q * l;
                elT[x * PB + m] = 0; erT[x * PB + m] = 0;
            }
            __syncthreads();

            // ---- stage: exp + transpose + bf16 cast ----
            const float* lbase = chart + (s0 * NN + s0) * S;   // left rows contiguous
            for (int i = tid; i < l * S; i += 384) {
                int r = i / S, x = i - r * S;
                float vl = lbase[i];
                float vr = chart[((s0 + r + 1) * NN + j) * S + x];
                elT[x * PB + r] = f2bf(__expf(vl - ml[r]) * wexp[r]);
                erT[x * PB + r] = f2bf(__expf(vr - mr[r]));
            }
            __syncthreads();

            // ---- G via MFMA: 6 waves x 6 col-tiles ----
            f32x4 acc[6];
            {
                f32x4 zz = {0.f, 0.f, 0.f, 0.f};
#pragma unroll
                for (int tc = 0; tc < 6; ++tc) acc[tc] = zz;
            }
            const int arow = w * 16 + (lane & 15);
            const int koff = (lane >> 4) * 8;
            for (int ks = 0; ks < (K >> 5); ++ks) {
                bf16x8 af = *(const bf16x8*)(elT + arow * PB + ks * 32 + koff);
#pragma unroll
                for (int tc = 0; tc < 6; ++tc) {
                    bf16x8 bfr = *(const bf16x8*)(erT + (tc * 16 + (lane & 15)) * PB + ks * 32 + koff);
                    acc[tc] = __builtin_amdgcn_mfma_f32_16x16x32_bf16(af, bfr, acc[tc], 0, 0, 0);
                }
            }

            // ---- contraction: 6 a's, bf16 tile loads (uint2 = 4 regs) ----
            float pv[ACH];
#pragma unroll
            for (int ai = 0; ai < ACH; ++ai) pv[ai] = 0.f;
#pragma unroll
            for (int ai = 0; ai < ACH; ++ai) {
                const unsigned short* rp = eruleB + ((a0 + ai) * 36 + w * 6) * 256 + lane * 4;
#pragma unroll
                for (int tc = 0; tc < 6; ++tc) {
                    uint2 rv = *(const uint2*)(rp + tc * 256);
                    float r0 = __uint_as_float((rv.x & 0xffffu) << 16);
                    float r1 = __uint_as_float(rv.x & 0xffff0000u);
                    float r2 = __uint_as_float((rv.y & 0xffffu) << 16);
                    float r3 = __uint_as_float(rv.y & 0xffff0000u);
                    pv[ai] += r0 * acc[tc][0] + r1 * acc[tc][1]
                            + r2 * acc[tc][2] + r3 * acc[tc][3];
                }
            }
#pragma unroll
            for (int ai = 0; ai < ACH; ++ai) {
                float p = pv[ai];
                for (int o = 32; o > 0; o >>= 1) p += __shfl_down(p, o);
                if (lane == 0) part[ai][w] = p;
            }
            __syncthreads();

            // ---- finalize chunk ----
            if (chunk == 0 && tid >= NT && tid < S)
                chart[cell * S + tid] = NEGF;
            if (tid < ACH) {
                float sum = part[tid][0] + part[tid][1] + part[tid][2]
                          + part[tid][3] + part[tid][4] + part[tid][5];
                float alpha = Msh + Rm + logf(sum);
                chart[cell * S + a0 + tid] = alpha;
                atomicMax(&mkey[cell], ordKey(alpha));
            }
        }
        grid.sync();
    }

    // ---- final root logsumexp (block 0, wave 0) ----
    if (blockIdx.x == 0 && w == 0) {
        float v = (lane < NT) ? chart[(NN - 1) * S + lane] + root[lane] : -INFINITY;
        float m = v;
        for (int o = 32; o > 0; o >>= 1) m = fmaxf(m, __shfl_down(m, o));
        m = __shfl(m, 0);
        float e = (lane < NT) ? __expf(v - m) : 0.f;
        for (int o = 32; o > 0; o >>= 1) e += __shfl_down(e, o);
        if (lane == 0) out[0] = m + logf(e);
    }
}

extern "C" void kernel_launch(void* const* d_in, const int* in_sizes, int n_in,
                              void* d_out, int out_size, void* d_ws, size_t ws_size,
                              hipStream_t stream) {
    const float* unary = (const float*)d_in[0];  // (48,60)
    const float* rule  = (const float*)d_in[1];  // (30,90,90)
    const float* root  = (const float*)d_in[2];  // (30,)
    float* out = (float*)d_out;

    float*          ws     = (float*)d_ws;
    unsigned short* eruleB = (unsigned short*)ws;          // 276480 ushorts (138240 floats)
    float*          chart  = ws + 138240;                  // 207360 floats
    float*          rpart  = chart + NN * NN * S;          // 128
    float*          rmax   = rpart + 128;                  // 1 (+3 pad)
    unsigned*       mkey   = (unsigned*)(rmax + 4);        // 2304

    k_rmax1 <<<128, 256, 0, stream>>>(rule, rpart);
    k_rmax2 <<<1, 64, 0, stream>>>(rpart, rmax);
    k_eruleB<<<dim3(30, 36), 64, 0, stream>>>(rule, rmax, eruleB);
    k_init  <<<NN, 96, 0, stream>>>(unary, chart, mkey);

    void* args[6] = { (void*)&eruleB, (void*)&rmax, (void*)&root,
                      (void*)&chart, (void*)&mkey, (void*)&out };
    hipLaunchCooperativeKernel((const void*)k_coop, dim3(NBLKC), dim3(384),
                               args, 0, stream);
}

// Round 9
// 401.421 us; speedup vs baseline: 3.5702x; 3.5702x over previous
//
#include <hip/hip_runtime.h>
#include <math.h>

#define NT 30
#define TT 60
#define S  90
#define NN 48
#define SS (S*S)            // 8100
#define RSZ (NT*SS)         // 243000
#define NEGF (-1.0e9f)
#define PB 72               // bf16 LDS pitch (144B, 16B-aligned)

typedef __attribute__((ext_vector_type(8))) short bf16x8;
typedef __attribute__((ext_vector_type(4))) float f32x4;

__device__ __forceinline__ unsigned ordKey(float f) {
    unsigned u = __float_as_uint(f);
    return (u & 0x80000000u) ? ~u : (u | 0x80000000u);
}
__device__ __forceinline__ float decKey(unsigned k) {
    unsigned u = (k & 0x80000000u) ? (k ^ 0x80000000u) : ~k;
    return __uint_as_float(u);
}
__device__ __forceinline__ unsigned short f2bf(float f) {
    unsigned u = __float_as_uint(f);
    return (unsigned short)((u + 0x7fffu + ((u >> 16) & 1u)) >> 16);
}
__device__ __forceinline__ float bf2f(unsigned short h) {
    return __uint_as_float(((unsigned)h) << 16);
}

// 128 blocks x 256: rule-max partials; blocks 0..47 also init diag svec/scal/mkey.
__global__ void k_rmax1init(const float* __restrict__ rule, const float* __restrict__ unary,
                            float* __restrict__ rpart, unsigned short* __restrict__ svec,
                            float* __restrict__ scal, unsigned* __restrict__ mkey) {
    __shared__ float red[256];
    __shared__ float mxs;
    float v = -INFINITY;
    for (int i = blockIdx.x * 256 + threadIdx.x; i < RSZ; i += 256 * 128)
        v = fmaxf(v, rule[i]);
    red[threadIdx.x] = v;
    __syncthreads();
    for (int s = 128; s > 0; s >>= 1) {
        if (threadIdx.x < s) red[threadIdx.x] = fmaxf(red[threadIdx.x], red[threadIdx.x + s]);
        __syncthreads();
    }
    if (threadIdx.x == 0) rpart[blockIdx.x] = red[0];

    const int i = blockIdx.x;
    if (i < NN) {
        const int t = threadIdx.x;
        if (t < 64) {
            float u = (t < TT) ? unary[i * TT + t] : -INFINITY;
            for (int o = 32; o > 0; o >>= 1) u = fmaxf(u, __shfl_down(u, o));
            if (t == 0) mxs = u;
        }
        __syncthreads();
        const float mx = mxs;
        if (t < 96)
            svec[(i * NN + i) * 96 + t] =
                (t >= NT && t < S) ? f2bf(__expf(unary[i * TT + (t - NT)] - mx)) : (unsigned short)0;
        if (t == 0) scal[i * NN + i] = mx;
        if (t < NN) mkey[i * NN + t] = (t == i) ? ordKey(mx) : 0u;
    }
}

// grid (30,36) x 64: finish rule-max reduce inline; write bf16 tile-major erule.
__global__ void k_eruleB(const float* __restrict__ rule, const float* __restrict__ rpart,
                         float* __restrict__ rmax, unsigned short* __restrict__ eruleB) {
    const int a    = blockIdx.x;
    const int tIdx = blockIdx.y;
    const int lane = threadIdx.x;   // 64
    float v = fmaxf(rpart[lane], rpart[lane + 64]);
    for (int o = 32; o > 0; o >>= 1) v = fmaxf(v, __shfl_down(v, o));
    const float Rm = __shfl(v, 0);
    if (a == 0 && tIdx == 0 && lane == 0) rmax[0] = Rm;

    const int bt = tIdx / 6, ct = tIdx - bt * 6;
    ushort4 vv;
    unsigned short* pv = (unsigned short*)&vv;
#pragma unroll
    for (int reg = 0; reg < 4; ++reg) {
        int b = bt * 16 + (lane >> 4) * 4 + reg;
        int c = ct * 16 + (lane & 15);
        float val = (b < S && c < S) ? __expf(rule[a * SS + b * S + c] - Rm) : 0.f;
        pv[reg] = f2bf(val);
    }
    *(ushort4*)(eruleB + ((a * 36 + tIdx) * 64 + lane) * 4) = vv;
}

// One block per (span, a-chunk). LAST: single block, all 30 a's + root logsumexp.
template <int NACH, bool LAST>
__global__ __launch_bounds__(384, 1) void k_level(int l,
                                                  const unsigned short* __restrict__ eruleB,
                                                  const float* __restrict__ rmax,
                                                  const float* __restrict__ root,
                                                  unsigned short* __restrict__ svec,
                                                  float* __restrict__ scal,
                                                  unsigned* __restrict__ mkey,
                                                  float* __restrict__ out) {
    const int s0   = blockIdx.x;
    const int chunk= blockIdx.y;
    const int j    = s0 + l;
    const int a0   = chunk * NACH;
    const int cell = s0 * NN + j;
    const int tid  = threadIdx.x;
    const int lane = tid & 63;
    const int w    = tid >> 6;

    __shared__ unsigned short elT[96 * PB];
    __shared__ unsigned short erT[96 * PB];
    __shared__ float fL[47], fR[47];
    __shared__ float part[30][6];
    __shared__ float alph[30];
    __shared__ float Msh;

    const float Rm = rmax[0];

    // ---- wave 0: per-split scales/factors from scal/mkey tables ----
    if (w == 0) {
        float msum = -INFINITY, sl = 0.f, sr = 0.f, mrv = 0.f;
        if (lane < l) {
            int cl = s0 * NN + s0 + lane;
            int cr = (s0 + lane + 1) * NN + j;
            float mlv = decKey(mkey[cl]);
            mrv = decKey(mkey[cr]);
            sl = scal[cl]; sr = scal[cr];
            msum = mlv + mrv;
        }
        float v = msum;
        for (int o = 32; o > 0; o >>= 1) v = fmaxf(v, __shfl_down(v, o));
        float M = __shfl(v, 0);
        if (lane == 0) Msh = M;
        if (lane < l) {
            fL[lane] = __expf(sl + mrv - M);   // exp(scalL - mL) * exp(mL + mR - M)
            fR[lane] = __expf(sr - mrv);
        }
    }

    // ---- zero K-pad regions ----
    const int K  = (l > 32) ? 64 : 32;
    const int zc = K - l;
    for (int i = tid; i < 96 * zc; i += 384) {
        int x = i / zc, m = l + (i - x * zc);
        elT[x * PB + m] = 0; erT[x * PB + m] = 0;
    }
    for (int i = tid; i < 6 * l; i += 384) {
        int q = i / l;
        int x = S + q, m = i - q * l;
        elT[x * PB + m] = 0; erT[x * PB + m] = 0;
    }
    __syncthreads();

    // ---- stage: bf16 load * per-row factor, transpose ----
    const unsigned short* lb = svec + (s0 * NN + s0) * 96;   // left cells contiguous
    for (int i = tid; i < l * S; i += 384) {
        int r = i / S, x = i - r * S;
        float vl = bf2f(lb[r * 96 + x]) * fL[r];
        float vr = bf2f(svec[((s0 + r + 1) * NN + j) * 96 + x]) * fR[r];
        elT[x * PB + r] = f2bf(vl);
        erT[x * PB + r] = f2bf(vr);
    }
    __syncthreads();

    // ---- G via MFMA: 6 waves x 6 col-tiles ----
    f32x4 acc[6];
    {
        f32x4 zz = {0.f, 0.f, 0.f, 0.f};
#pragma unroll
        for (int tc = 0; tc < 6; ++tc) acc[tc] = zz;
    }
    const int arow = w * 16 + (lane & 15);
    const int koff = (lane >> 4) * 8;
    for (int ks = 0; ks < (K >> 5); ++ks) {
        bf16x8 af = *(const bf16x8*)(elT + arow * PB + ks * 32 + koff);
#pragma unroll
        for (int tc = 0; tc < 6; ++tc) {
            bf16x8 bfr = *(const bf16x8*)(erT + (tc * 16 + (lane & 15)) * PB + ks * 32 + koff);
            acc[tc] = __builtin_amdgcn_mfma_f32_16x16x32_bf16(af, bfr, acc[tc], 0, 0, 0);
        }
    }

    // ---- contraction vs bf16 tile-major erule ----
    float pv[NACH];
#pragma unroll
    for (int ai = 0; ai < NACH; ++ai) pv[ai] = 0.f;
#pragma unroll
    for (int ai = 0; ai < NACH; ++ai) {
        const unsigned short* rp = eruleB + ((a0 + ai) * 36 + w * 6) * 256 + lane * 4;
#pragma unroll
        for (int tc = 0; tc < 6; ++tc) {
            uint2 rv = *(const uint2*)(rp + tc * 256);
            float r0 = __uint_as_float((rv.x & 0xffffu) << 16);
            float r1 = __uint_as_float(rv.x & 0xffff0000u);
            float r2 = __uint_as_float((rv.y & 0xffffu) << 16);
            float r3 = __uint_as_float(rv.y & 0xffff0000u);
            pv[ai] += r0 * acc[tc][0] + r1 * acc[tc][1]
                    + r2 * acc[tc][2] + r3 * acc[tc][3];
        }
    }
#pragma unroll
    for (int ai = 0; ai < NACH; ++ai) {
        float p = pv[ai];
        for (int o = 32; o > 0; o >>= 1) p += __shfl_down(p, o);
        if (lane == 0) part[ai][w] = p;
    }
    __syncthreads();

    // ---- finalize ----
    if (!LAST) {
        if (chunk == 0) {
            if (tid >= NT && tid < 96) svec[cell * 96 + tid] = 0;
            if (tid == 0) scal[cell] = Msh + Rm;
        }
        if (tid < NACH) {
            float sum = part[tid][0] + part[tid][1] + part[tid][2]
                      + part[tid][3] + part[tid][4] + part[tid][5];
            float alpha = Msh + Rm + logf(sum);
            svec[cell * 96 + a0 + tid] = f2bf(sum);
            atomicMax(&mkey[cell], ordKey(alpha));
        }
    } else {
        if (tid < NT) {
            float sum = part[tid][0] + part[tid][1] + part[tid][2]
                      + part[tid][3] + part[tid][4] + part[tid][5];
            alph[tid] = Msh + Rm + logf(sum) + root[tid];
        }
        __syncthreads();
        if (w == 0) {
            float v = (lane < NT) ? alph[lane] : -INFINITY;
            float m = v;
            for (int o = 32; o > 0; o >>= 1) m = fmaxf(m, __shfl_down(m, o));
            m = __shfl(m, 0);
            float e = (lane < NT) ? __expf(v - m) : 0.f;
            for (int o = 32; o > 0; o >>= 1) e += __shfl_down(e, o);
            if (lane == 0) out[0] = m + logf(e);
        }
    }
}

extern "C" void kernel_launch(void* const* d_in, const int* in_sizes, int n_in,
                              void* d_out, int out_size, void* d_ws, size_t ws_size,
                              hipStream_t stream) {
    const float* unary = (const float*)d_in[0];  // (48,60)
    const float* rule  = (const float*)d_in[1];  // (30,90,90)
    const float* root  = (const float*)d_in[2];  // (30,)
    float* out = (float*)d_out;

    float*          ws     = (float*)d_ws;
    unsigned short* eruleB = (unsigned short*)ws;           // 276480 ushorts
    unsigned short* svec   = eruleB + 30 * 36 * 256;        // 48*48*96 = 221184 ushorts
    float*          scal   = (float*)(svec + NN * NN * 96); // 2304 floats
    float*          rpart  = scal + NN * NN;                // 128
    float*          rmax   = rpart + 128;                   // 1 (+3 pad)
    unsigned*       mkey   = (unsigned*)(rmax + 4);         // 2304

    k_rmax1init<<<128, 256, 0, stream>>>(rule, unary, rpart, svec, scal, mkey);
    k_eruleB<<<dim3(30, 36), 64, 0, stream>>>(rule, rpart, rmax, eruleB);
    for (int l = 1; l < NN - 1; ++l) {
        k_level<6, false><<<dim3(NN - l, 5), 384, 0, stream>>>(
            l, eruleB, rmax, root, svec, scal, mkey, out);
    }
    k_level<30, true><<<dim3(1, 1), 384, 0, stream>>>(
        NN - 1, eruleB, rmax, root, svec, scal, mkey, out);
}

// Round 10
// 301.852 us; speedup vs baseline: 4.7479x; 1.3299x over previous
//
#include <hip/hip_runtime.h>
#include <math.h>

#define NT 30
#define TT 60
#define S  90
#define NN 48
#define SS (S*S)            // 8100
#define RSZ (NT*SS)         // 243000
#define PB 72               // bf16 LDS pitch (144B, 16B-aligned)

typedef __attribute__((ext_vector_type(8))) short bf16x8;
typedef __attribute__((ext_vector_type(4))) float f32x4;

__device__ __forceinline__ unsigned ordKey(float f) {
    unsigned u = __float_as_uint(f);
    return (u & 0x80000000u) ? ~u : (u | 0x80000000u);
}
__device__ __forceinline__ float decKey(unsigned k) {
    unsigned u = (k & 0x80000000u) ? (k ^ 0x80000000u) : ~k;
    return __uint_as_float(u);
}
__device__ __forceinline__ unsigned short f2bf(float f) {
    unsigned u = __float_as_uint(f);
    return (unsigned short)((u + 0x7fffu + ((u >> 16) & 1u)) >> 16);
}
__device__ __forceinline__ float bf2f(unsigned short h) {
    return __uint_as_float(((unsigned)h) << 16);
}

// 128 blocks x 256: rule-max partials; blocks 0..47 also init diag svec/scal/mkey.
__global__ void k_rmax1init(const float* __restrict__ rule, const float* __restrict__ unary,
                            float* __restrict__ rpart, unsigned short* __restrict__ svec,
                            float* __restrict__ scal, unsigned* __restrict__ mkey) {
    __shared__ float red[256];
    __shared__ float mxs;
    float v = -INFINITY;
    for (int i = blockIdx.x * 256 + threadIdx.x; i < RSZ; i += 256 * 128)
        v = fmaxf(v, rule[i]);
    red[threadIdx.x] = v;
    __syncthreads();
    for (int s = 128; s > 0; s >>= 1) {
        if (threadIdx.x < s) red[threadIdx.x] = fmaxf(red[threadIdx.x], red[threadIdx.x + s]);
        __syncthreads();
    }
    if (threadIdx.x == 0) rpart[blockIdx.x] = red[0];

    const int i = blockIdx.x;
    if (i < NN) {
        const int t = threadIdx.x;
        if (t < 64) {
            float u = (t < TT) ? unary[i * TT + t] : -INFINITY;
            for (int o = 32; o > 0; o >>= 1) u = fmaxf(u, __shfl_down(u, o));
            if (t == 0) mxs = u;
        }
        __syncthreads();
        const float mx = mxs;
        if (t < 96)
            svec[(i * NN + i) * 96 + t] =
                (t >= NT && t < S) ? f2bf(__expf(unary[i * TT + (t - NT)] - mx)) : (unsigned short)0;
        if (t == 0) scal[i * NN + i] = mx;
        if (t < NN) mkey[i * NN + t] = (t == i) ? ordKey(mx) : 0u;
    }
}

// grid (30,36) x 64: finish rule-max reduce inline; write bf16 tile-major erule.
__global__ void k_eruleB(const float* __restrict__ rule, const float* __restrict__ rpart,
                         unsigned short* __restrict__ eruleB) {
    const int a    = blockIdx.x;
    const int tIdx = blockIdx.y;
    const int lane = threadIdx.x;   // 64
    float v = fmaxf(rpart[lane], rpart[lane + 64]);
    for (int o = 32; o > 0; o >>= 1) v = fmaxf(v, __shfl_down(v, o));
    const float Rm = __shfl(v, 0);

    const int bt = tIdx / 6, ct = tIdx - bt * 6;
    ushort4 vv;
    unsigned short* pv = (unsigned short*)&vv;
#pragma unroll
    for (int reg = 0; reg < 4; ++reg) {
        int b = bt * 16 + (lane >> 4) * 4 + reg;
        int c = ct * 16 + (lane & 15);
        float val = (b < S && c < S) ? __expf(rule[a * SS + b * S + c] - Rm) : 0.f;
        pv[reg] = f2bf(val);
    }
    *(ushort4*)(eruleB + ((a * 36 + tIdx) * 64 + lane) * 4) = vv;
}

// grid (NN-l, 30): one block per (span, nonterminal).
__global__ __launch_bounds__(384, 1) void k_level(int l,
                                                  const unsigned short* __restrict__ eruleB,
                                                  const float* __restrict__ rpart,
                                                  unsigned short* __restrict__ svec,
                                                  float* __restrict__ scal,
                                                  unsigned* __restrict__ mkey) {
    const int s0   = blockIdx.x;
    const int a    = blockIdx.y;
    const int j    = s0 + l;
    const int cell = s0 * NN + j;
    const int tid  = threadIdx.x;
    const int lane = tid & 63;
    const int w    = tid >> 6;

    __shared__ unsigned short elT[96 * PB];
    __shared__ unsigned short erT[96 * PB];
    __shared__ float fL[47], fR[47];
    __shared__ float part[6];
    __shared__ float Msh, Rmsh;

    // ---- wave 0: per-split factors; wave 1 lane 0: rule max ----
    if (w == 1 && lane == 0) {
        float r0 = rpart[0];
        // rpart fully reduced? no — reduce 128 serially is slow; use wave below.
        Rmsh = r0;  // placeholder, overwritten below
    }
    if (w == 1) {
        float v = fmaxf(rpart[lane], rpart[lane + 64]);
        for (int o = 32; o > 0; o >>= 1) v = fmaxf(v, __shfl_down(v, o));
        if (lane == 0) Rmsh = v;
    }
    if (w == 0) {
        float msum = -INFINITY, sl = 0.f, sr = 0.f, mrv = 0.f;
        if (lane < l) {
            int cl = s0 * NN + s0 + lane;
            int cr = (s0 + lane + 1) * NN + j;
            float mlv = decKey(mkey[cl]);
            mrv = decKey(mkey[cr]);
            sl = scal[cl]; sr = scal[cr];
            msum = mlv + mrv;
        }
        float v = msum;
        for (int o = 32; o > 0; o >>= 1) v = fmaxf(v, __shfl_down(v, o));
        float M = __shfl(v, 0);
        if (lane == 0) Msh = M;
        if (lane < l) {
            fL[lane] = __expf(sl + mrv - M);
            fR[lane] = __expf(sr - mrv);
        }
    }

    // ---- full zero of LDS tiles (uint4) ----
    {
        uint4 z = {0u, 0u, 0u, 0u};
        uint4* z1 = (uint4*)elT;
        uint4* z2 = (uint4*)erT;
        const int n16 = 96 * PB / 8;   // 864 uint4 per array
        for (int i = tid; i < n16; i += 384) { z1[i] = z; z2[i] = z; }
    }
    __syncthreads();

    // ---- stage: bf16 load * per-row factor, transpose ----
    const unsigned short* lb = svec + (s0 * NN + s0) * 96;   // left cells contiguous
    for (int i = tid; i < l * S; i += 384) {
        int r = i / S, x = i - r * S;
        float vl = bf2f(lb[r * 96 + x]) * fL[r];
        float vr = bf2f(svec[((s0 + r + 1) * NN + j) * 96 + x]) * fR[r];
        elT[x * PB + r] = f2bf(vl);
        erT[x * PB + r] = f2bf(vr);
    }
    __syncthreads();

    // ---- G via MFMA: 6 waves x 6 col-tiles ----
    const int K = (l > 32) ? 64 : 32;
    f32x4 acc[6];
    {
        f32x4 zz = {0.f, 0.f, 0.f, 0.f};
#pragma unroll
        for (int tc = 0; tc < 6; ++tc) acc[tc] = zz;
    }
    const int arow = w * 16 + (lane & 15);
    const int koff = (lane >> 4) * 8;
    for (int ks = 0; ks < (K >> 5); ++ks) {
        bf16x8 af = *(const bf16x8*)(elT + arow * PB + ks * 32 + koff);
#pragma unroll
        for (int tc = 0; tc < 6; ++tc) {
            bf16x8 bfr = *(const bf16x8*)(erT + (tc * 16 + (lane & 15)) * PB + ks * 32 + koff);
            acc[tc] = __builtin_amdgcn_mfma_f32_16x16x32_bf16(af, bfr, acc[tc], 0, 0, 0);
        }
    }

    // ---- contraction vs bf16 tile-major erule (single a) ----
    float p = 0.f;
    {
        const unsigned short* rp = eruleB + (a * 36 + w * 6) * 256 + lane * 4;
#pragma unroll
        for (int tc = 0; tc < 6; ++tc) {
            uint2 rv = *(const uint2*)(rp + tc * 256);
            float r0 = __uint_as_float((rv.x & 0xffffu) << 16);
            float r1 = __uint_as_float(rv.x & 0xffff0000u);
            float r2 = __uint_as_float((rv.y & 0xffffu) << 16);
            float r3 = __uint_as_float(rv.y & 0xffff0000u);
            p += r0 * acc[tc][0] + r1 * acc[tc][1]
               + r2 * acc[tc][2] + r3 * acc[tc][3];
        }
    }
    for (int o = 32; o > 0; o >>= 1) p += __shfl_down(p, o);
    if (lane == 0) part[w] = p;
    __syncthreads();

    // ---- finalize ----
    if (a == 0) {
        if (tid >= NT && tid < 96) svec[cell * 96 + tid] = 0;
        if (tid == 0) scal[cell] = Msh + Rmsh;
    }
    if (tid == 0) {
        float sum = part[0] + part[1] + part[2] + part[3] + part[4] + part[5];
        float alpha = Msh + Rmsh + logf(sum);
        svec[cell * 96 + a] = f2bf(sum);
        atomicMax(&mkey[cell], ordKey(alpha));
    }
}

__global__ void k_final(const float* __restrict__ root, const unsigned short* __restrict__ svec,
                        const float* __restrict__ scal, float* __restrict__ out) {
    const int t = threadIdx.x;  // 64
    const int cell = NN - 1;    // (0, 47)
    float v = (t < NT) ? scal[cell] + logf(bf2f(svec[cell * 96 + t])) + root[t] : -INFINITY;
    float m = v;
    for (int o = 32; o > 0; o >>= 1) m = fmaxf(m, __shfl_down(m, o));
    m = __shfl(m, 0);
    float e = (t < NT) ? __expf(v - m) : 0.f;
    for (int o = 32; o > 0; o >>= 1) e += __shfl_down(e, o);
    if (t == 0) out[0] = m + logf(e);
}

extern "C" void kernel_launch(void* const* d_in, const int* in_sizes, int n_in,
                              void* d_out, int out_size, void* d_ws, size_t ws_size,
                              hipStream_t stream) {
    const float* unary = (const float*)d_in[0];  // (48,60)
    const float* rule  = (const float*)d_in[1];  // (30,90,90)
    const float* root  = (const float*)d_in[2];  // (30,)
    float* out = (float*)d_out;

    float*          ws     = (float*)d_ws;
    unsigned short* eruleB = (unsigned short*)ws;           // 276480 ushorts
    unsigned short* svec   = eruleB + 30 * 36 * 256;        // 221184 ushorts
    float*          scal   = (float*)(svec + NN * NN * 96); // 2304 floats
    float*          rpart  = scal + NN * NN;                // 128
    unsigned*       mkey   = (unsigned*)(rpart + 128);      // 2304

    k_rmax1init<<<128, 256, 0, stream>>>(rule, unary, rpart, svec, scal, mkey);
    k_eruleB<<<dim3(30, 36), 64, 0, stream>>>(rule, rpart, eruleB);
    for (int l = 1; l < NN; ++l) {
        k_level<<<dim3(NN - l, 30), 384, 0, stream>>>(l, eruleB, rpart, svec, scal, mkey);
    }
    k_final<<<1, 64, 0, stream>>>(root, svec, scal, out);
}